// Round 7
// baseline (216.209 us; speedup 1.0000x reference)
//
#include <hip/hip_runtime.h>
#include <hip/hip_bf16.h>

// Problem constants (from reference)
#define B 16
#define C 128
#define H 192
#define W 192
#define HID 32
#define K 2
#define PLANE (H*W)           // 36864
#define NPLANES (B*C)         // 2048
#define RB 8                  // output rows per thread (vertical register blocking)
#define CHUNK_PLANES 512      // 4 samples per chunk
#define NCHUNKS 4

typedef float floatx4 __attribute__((ext_vector_type(4)));

// ---------------- Fused pool/conv kernel ----------------
// Block = 384 threads (6 waves). Two block-uniform roles:
//  POOL: one block pools one plane (global mean) -> pooled[plane].
//  CONV: one block computes 1/3 plane of depthwise 3x3 conv + bias.
//        The per-sample selector MLP+softmax is recomputed in-block from
//        pooled[] (written by the PREVIOUS launch; L2/L3-hot, 512 B).
// Pipeline across launches: conv(chunk c) runs concurrently with
// pool(chunk c+1); conv's input chunk is L3-resident from the previous
// launch's pool stream (proven retention in R4: FETCH 302->162 MB).
// Out-stores are nontemporal so the write stream never evicts x from L3.
__global__ __launch_bounds__(384) void fused_kernel(const float* __restrict__ x,
                                                    const float* __restrict__ w1,
                                                    const float* __restrict__ b1,
                                                    const float* __restrict__ w2,
                                                    const float* __restrict__ b2,
                                                    const float* __restrict__ wb,
                                                    const float* __restrict__ bias,
                                                    float* __restrict__ pooled,
                                                    float* __restrict__ out,
                                                    int convBase, int poolBase,
                                                    int doConv, int doPool) {
    const int tid = threadIdx.x;

    __shared__ float red[6];        // pool reduction
    __shared__ float sh[HID];       // selector hidden
    __shared__ float sAtt[K];       // selector attn
    __shared__ float sw[9];         // combined 3x3 weights for this block's (b,c)

    // ---- role decode (block-uniform) ----
    bool isPool;
    int poolPlane = 0, convIdx = 0;
    if (doPool && doConv) {
        isPool = ((blockIdx.x & 3) == 3);
        poolPlane = poolBase + (blockIdx.x >> 2);
        convIdx = (blockIdx.x >> 2) * 3 + (blockIdx.x & 3);
    } else if (doPool) {
        isPool = true;
        poolPlane = poolBase + blockIdx.x;
    } else {
        isPool = false;
        convIdx = blockIdx.x;
    }

    if (isPool) {
        // ---------------- POOL role ----------------
        const float4* px4 = (const float4*)(x + (size_t)poolPlane * PLANE); // 9216 vec4
        float s = 0.f;
        #pragma unroll
        for (int it = 0; it < PLANE / 4 / 384; ++it) {   // 24 iterations exact
            float4 v = px4[tid + it * 384];
            s += v.x + v.y + v.z + v.w;
        }
        for (int off = 32; off; off >>= 1) s += __shfl_down(s, off, 64);
        const int lane = tid & 63, wid = tid >> 6;
        if (lane == 0) red[wid] = s;
        __syncthreads();
        if (tid == 0) {
            float t = red[0] + red[1] + red[2] + red[3] + red[4] + red[5];
            pooled[poolPlane] = t * (1.0f / (float)PLANE);
        }
        return;
    }

    // ---------------- CONV role ----------------
    const int plane = convBase + convIdx / 3;   // b*C + c (block-uniform)
    const int seg   = convIdx % 3;
    const int c     = plane & (C - 1);
    const int smp   = plane >> 7;               // plane / C

    // --- in-block selector: h = relu(pooled[b,:] @ w1.T + b1) ---
    if (tid < HID) {
        float s = b1[tid];
        const float* pb = pooled + smp * C;
        const float* wj = w1 + tid * C;
        #pragma unroll 8
        for (int cc = 0; cc < C; ++cc) s += pb[cc] * wj[cc];
        sh[tid] = fmaxf(s, 0.f);
    }
    __syncthreads();
    if (tid < K) {
        float s = b2[tid];
        const float* wk = w2 + tid * HID;
        #pragma unroll
        for (int j = 0; j < HID; ++j) s += sh[j] * wk[j];
        sAtt[tid] = s;
    }
    __syncthreads();
    if (tid == 0) {
        const float a0 = sAtt[0], a1 = sAtt[1];
        const float m = fmaxf(a0, a1);
        const float e0 = __expf(a0 - m), e1 = __expf(a1 - m);
        const float inv = 1.f / (e0 + e1);
        sAtt[0] = e0 * inv;
        sAtt[1] = e1 * inv;
    }
    __syncthreads();
    if (tid < 9) {
        sw[tid] = sAtt[0] * wb[c * 9 + tid] + sAtt[1] * wb[C * 9 + c * 9 + tid];
    }
    __syncthreads();

    const float w00 = sw[0], w01 = sw[1], w02 = sw[2];
    const float w10 = sw[3], w11 = sw[4], w12 = sw[5];
    const float w20 = sw[6], w21 = sw[7], w22 = sw[8];
    const float bv = bias[c];

    // thread = 4-wide x 8-tall tile; 8 bands x 48 strips per segment
    const int xq   = tid % 48;
    const int band = tid / 48 + seg * 8;   // 0..23
    const int x0 = xq * 4;
    const int y0 = band * RB;
    const float* px = x + (size_t)plane * PLANE;

    float acc[RB][4];
    #pragma unroll
    for (int j = 0; j < RB; ++j) {
        acc[j][0] = bv; acc[j][1] = bv; acc[j][2] = bv; acc[j][3] = bv;
    }

    #pragma unroll
    for (int i = 0; i < RB + 2; ++i) {
        const int r = y0 - 1 + i;
        float v0, v1, v2, v3, v4, v5;
        if (r >= 0 && r < H) {
            const float* rp = px + r * W + x0;
            const float4 cur = *(const float4*)rp;
            v1 = cur.x; v2 = cur.y; v3 = cur.z; v4 = cur.w;
            v0 = (x0 > 0)     ? rp[-1] : 0.f;
            v5 = (x0 + 4 < W) ? rp[4]  : 0.f;
        } else {
            v0 = v1 = v2 = v3 = v4 = v5 = 0.f;
        }
        // input row r is the TOP tap of out row i, MID of i-1, BOTTOM of i-2
        if (i < RB) {
            acc[i][0] = fmaf(w00, v0, fmaf(w01, v1, fmaf(w02, v2, acc[i][0])));
            acc[i][1] = fmaf(w00, v1, fmaf(w01, v2, fmaf(w02, v3, acc[i][1])));
            acc[i][2] = fmaf(w00, v2, fmaf(w01, v3, fmaf(w02, v4, acc[i][2])));
            acc[i][3] = fmaf(w00, v3, fmaf(w01, v4, fmaf(w02, v5, acc[i][3])));
        }
        if (i >= 1 && i <= RB) {
            acc[i-1][0] = fmaf(w10, v0, fmaf(w11, v1, fmaf(w12, v2, acc[i-1][0])));
            acc[i-1][1] = fmaf(w10, v1, fmaf(w11, v2, fmaf(w12, v3, acc[i-1][1])));
            acc[i-1][2] = fmaf(w10, v2, fmaf(w11, v3, fmaf(w12, v4, acc[i-1][2])));
            acc[i-1][3] = fmaf(w10, v3, fmaf(w11, v4, fmaf(w12, v5, acc[i-1][3])));
        }
        if (i >= 2) {
            acc[i-2][0] = fmaf(w20, v0, fmaf(w21, v1, fmaf(w22, v2, acc[i-2][0])));
            acc[i-2][1] = fmaf(w20, v1, fmaf(w21, v2, fmaf(w22, v3, acc[i-2][1])));
            acc[i-2][2] = fmaf(w20, v2, fmaf(w21, v3, fmaf(w22, v4, acc[i-2][2])));
            acc[i-2][3] = fmaf(w20, v3, fmaf(w21, v4, fmaf(w22, v5, acc[i-2][3])));
        }
    }

    float* po = out + (size_t)plane * PLANE + y0 * W + x0;
    #pragma unroll
    for (int j = 0; j < RB; ++j) {
        floatx4 o = { acc[j][0], acc[j][1], acc[j][2], acc[j][3] };
        __builtin_nontemporal_store(o, (floatx4*)(po + j * W));
    }
}

extern "C" void kernel_launch(void* const* d_in, const int* in_sizes, int n_in,
                              void* d_out, int out_size, void* d_ws, size_t ws_size,
                              hipStream_t stream) {
    const float* x    = (const float*)d_in[0];
    const float* w1   = (const float*)d_in[1];
    const float* b1   = (const float*)d_in[2];
    const float* w2   = (const float*)d_in[3];
    const float* b2   = (const float*)d_in[4];
    const float* wb   = (const float*)d_in[5];
    const float* bias = (const float*)d_in[6];
    float* out = (float*)d_out;

    float* pooled = (float*)d_ws;   // [2048]

    // L0: pool chunk 0
    fused_kernel<<<CHUNK_PLANES, 384, 0, stream>>>(
        x, w1, b1, w2, b2, wb, bias, pooled, out,
        /*convBase*/0, /*poolBase*/0, /*doConv*/0, /*doPool*/1);

    // L1..L3: conv chunk c  ||  pool chunk c+1
    for (int c = 0; c < NCHUNKS - 1; ++c) {
        fused_kernel<<<CHUNK_PLANES * 4, 384, 0, stream>>>(
            x, w1, b1, w2, b2, wb, bias, pooled, out,
            /*convBase*/c * CHUNK_PLANES, /*poolBase*/(c + 1) * CHUNK_PLANES,
            /*doConv*/1, /*doPool*/1);
    }

    // L4: conv chunk 3
    fused_kernel<<<CHUNK_PLANES * 3, 384, 0, stream>>>(
        x, w1, b1, w2, b2, wb, bias, pooled, out,
        /*convBase*/(NCHUNKS - 1) * CHUNK_PLANES, /*poolBase*/0,
        /*doConv*/1, /*doPool*/0);
}

// Round 8
// 162.793 us; speedup vs baseline: 1.3281x; 1.3281x over previous
//
#include <hip/hip_runtime.h>
#include <hip/hip_bf16.h>

// Problem constants (from reference)
#define B 16
#define C 128
#define H 192
#define W 192
#define HID 32
#define K 2
#define PLANE (H*W)           // 36864
#define NPLANES (B*C)         // 2048

// conv tiling
#define TBLK 384              // threads per conv block (6 waves)
#define TROWS 32              // output rows per block
#define SROWS 34              // staged rows (with halo)
#define LDST 196              // LDS row stride in floats (49 float4)
#define SEGS (H / TROWS)      // 6 blocks per plane

typedef float floatx4 __attribute__((ext_vector_type(4)));

// ---------------- Kernel 1: global average pool per (b,c) plane ----------------
__global__ __launch_bounds__(256) void pool_kernel(const float* __restrict__ x,
                                                   float* __restrict__ pooled) {
    const int plane = blockIdx.x;  // b*C + c
    const float4* px4 = (const float4*)(x + (size_t)plane * PLANE);  // 9216 float4
    float s = 0.f;
    for (int i = threadIdx.x; i < PLANE / 4; i += 256) {
        float4 v = px4[i];
        s += v.x + v.y + v.z + v.w;
    }
    for (int off = 32; off; off >>= 1) s += __shfl_down(s, off, 64);
    __shared__ float wsum[4];
    const int lane = threadIdx.x & 63, wid = threadIdx.x >> 6;
    if (lane == 0) wsum[wid] = s;
    __syncthreads();
    if (threadIdx.x == 0) {
        pooled[plane] = (wsum[0] + wsum[1] + wsum[2] + wsum[3]) * (1.0f / (float)PLANE);
    }
}

// ---------------- Kernel 2: selector MLP + softmax + weight combine ----------------
__global__ __launch_bounds__(512) void selector_kernel(const float* __restrict__ pooled,
                                                       const float* __restrict__ w1,
                                                       const float* __restrict__ b1,
                                                       const float* __restrict__ w2,
                                                       const float* __restrict__ b2,
                                                       const float* __restrict__ wb,
                                                       float* __restrict__ cw) {
    __shared__ float h[B][HID];
    __shared__ float attn[B][K];
    const int tid = threadIdx.x;

    {
        const int b = tid >> 5, j = tid & 31;
        float s = b1[j];
        const float* pb = pooled + b * C;
        const float* wj = w1 + j * C;
        #pragma unroll 8
        for (int c = 0; c < C; ++c) s += pb[c] * wj[c];
        h[b][j] = fmaxf(s, 0.f);
    }
    __syncthreads();
    if (tid < B * K) {
        const int b = tid >> 1, k = tid & 1;
        float s = b2[k];
        const float* wk = w2 + k * HID;
        #pragma unroll
        for (int j = 0; j < HID; ++j) s += h[b][j] * wk[j];
        attn[b][k] = s;
    }
    __syncthreads();
    if (tid < B) {
        const float a0 = attn[tid][0], a1 = attn[tid][1];
        const float m = fmaxf(a0, a1);
        const float e0 = __expf(a0 - m), e1 = __expf(a1 - m);
        const float inv = 1.f / (e0 + e1);
        attn[tid][0] = e0 * inv;
        attn[tid][1] = e1 * inv;
    }
    __syncthreads();
    for (int i = tid; i < B * C * 9; i += 512) {
        const int b = i / (C * 9);
        const int ci = i % (C * 9);
        cw[i] = attn[b][0] * wb[ci] + attn[b][1] * wb[C * 9 + ci];
    }
}

// ---------------- Kernel 3: depthwise 3x3 conv (pad 1) + bias, LDS-staged ----------------
// Block = 384 threads stages a 34-row x 192-col input tile into LDS ONCE
// (perfectly coalesced dwordx4, each cache line probed exactly once ->
// breaks the ~3 TB/s L1 tag-lookup wall of the register-tiled variants),
// then computes 32 output rows from LDS (3x row reuse + halos served at
// LDS bandwidth). Thread = 4-wide x 4-tall output tile.
__global__ __launch_bounds__(TBLK) void conv_kernel(const float* __restrict__ x,
                                                    const float* __restrict__ cw,
                                                    const float* __restrict__ bias,
                                                    float* __restrict__ out) {
    __shared__ float lds[SROWS * LDST];

    const int bid   = blockIdx.x;
    const int plane = bid / SEGS;          // forward, block-uniform
    const int seg   = bid % SEGS;
    const int tid   = threadIdx.x;
    const int c     = plane & (C - 1);
    const int y0    = seg * TROWS;

    const float* w = cw + plane * 9;
    const float w00 = w[0], w01 = w[1], w02 = w[2];
    const float w10 = w[3], w11 = w[4], w12 = w[5];
    const float w20 = w[6], w21 = w[7], w22 = w[8];
    const float bv = bias[c];

    // ---- stage 34 rows x 192 cols (48 float4 per row) into LDS ----
    const float4* px4 = (const float4*)(x + (size_t)plane * PLANE);
    float4* lds4 = (float4*)lds;
    #pragma unroll
    for (int k = 0; k < 5; ++k) {
        const int idx = tid + k * TBLK;          // 0..1631 (34*48)
        if (idx < SROWS * 48) {
            const int row  = idx / 48;           // staged row
            const int col4 = idx % 48;
            const int gRow = y0 - 1 + row;       // global image row
            float4 v = make_float4(0.f, 0.f, 0.f, 0.f);
            if (gRow >= 0 && gRow < H) v = px4[gRow * 48 + col4];
            lds4[row * 49 + col4] = v;
        }
    }
    __syncthreads();

    // ---- compute: thread = 4-wide x 4-tall ----
    const int xq   = tid % 48;      // col strip
    const int band = tid / 48;      // 0..7 (4 rows each)
    const int x0   = xq * 4;

    float acc[4][4];
    #pragma unroll
    for (int j = 0; j < 4; ++j) {
        acc[j][0] = bv; acc[j][1] = bv; acc[j][2] = bv; acc[j][3] = bv;
    }

    #pragma unroll
    for (int i = 0; i < 6; ++i) {
        const int sr = band * 4 + i;            // staged row index
        const float* lr = lds + sr * LDST;
        const floatx4 cur = *(const floatx4*)(lr + x0);
        const float v0 = (xq > 0)  ? lr[x0 - 1] : 0.f;
        const float v5 = (xq < 47) ? lr[x0 + 4] : 0.f;
        const float v1 = cur.x, v2 = cur.y, v3 = cur.z, v4 = cur.w;

        // staged row sr: TOP tap of out j=i, MID of j=i-1, BOTTOM of j=i-2
        if (i < 4) {
            acc[i][0] = fmaf(w00, v0, fmaf(w01, v1, fmaf(w02, v2, acc[i][0])));
            acc[i][1] = fmaf(w00, v1, fmaf(w01, v2, fmaf(w02, v3, acc[i][1])));
            acc[i][2] = fmaf(w00, v2, fmaf(w01, v3, fmaf(w02, v4, acc[i][2])));
            acc[i][3] = fmaf(w00, v3, fmaf(w01, v4, fmaf(w02, v5, acc[i][3])));
        }
        if (i >= 1 && i <= 4) {
            acc[i-1][0] = fmaf(w10, v0, fmaf(w11, v1, fmaf(w12, v2, acc[i-1][0])));
            acc[i-1][1] = fmaf(w10, v1, fmaf(w11, v2, fmaf(w12, v3, acc[i-1][1])));
            acc[i-1][2] = fmaf(w10, v2, fmaf(w11, v3, fmaf(w12, v4, acc[i-1][2])));
            acc[i-1][3] = fmaf(w10, v3, fmaf(w11, v4, fmaf(w12, v5, acc[i-1][3])));
        }
        if (i >= 2) {
            acc[i-2][0] = fmaf(w20, v0, fmaf(w21, v1, fmaf(w22, v2, acc[i-2][0])));
            acc[i-2][1] = fmaf(w20, v1, fmaf(w21, v2, fmaf(w22, v3, acc[i-2][1])));
            acc[i-2][2] = fmaf(w20, v2, fmaf(w21, v3, fmaf(w22, v4, acc[i-2][2])));
            acc[i-2][3] = fmaf(w20, v3, fmaf(w21, v4, fmaf(w22, v5, acc[i-2][3])));
        }
    }

    float* po = out + (size_t)plane * PLANE + (y0 + band * 4) * W + x0;
    #pragma unroll
    for (int j = 0; j < 4; ++j) {
        floatx4 o = { acc[j][0], acc[j][1], acc[j][2], acc[j][3] };
        __builtin_nontemporal_store(o, (floatx4*)(po + j * W));
    }
}

extern "C" void kernel_launch(void* const* d_in, const int* in_sizes, int n_in,
                              void* d_out, int out_size, void* d_ws, size_t ws_size,
                              hipStream_t stream) {
    const float* x    = (const float*)d_in[0];
    const float* w1   = (const float*)d_in[1];
    const float* b1   = (const float*)d_in[2];
    const float* w2   = (const float*)d_in[3];
    const float* b2   = (const float*)d_in[4];
    const float* wb   = (const float*)d_in[5];
    const float* bias = (const float*)d_in[6];
    float* out = (float*)d_out;

    float* pooled = (float*)d_ws;          // [2048]
    float* cw     = pooled + NPLANES;      // [2048*9]

    pool_kernel<<<NPLANES, 256, 0, stream>>>(x, pooled);
    selector_kernel<<<1, 512, 0, stream>>>(pooled, w1, b1, w2, b2, wb, cw);
    conv_kernel<<<NPLANES * SEGS, TBLK, 0, stream>>>(x, cw, bias, out);
}